// Round 13
// baseline (139.671 us; speedup 1.0000x reference)
//
#include <hip/hip_runtime.h>
#include <math.h>

#define Bsz 8
#define Nn 1024
#define Ff 512
#define Hh 4
#define Dd 128

typedef float f32x4 __attribute__((ext_vector_type(4)));
typedef short bf16x8 __attribute__((ext_vector_type(8)));

#define LOG2E 1.44269504f

__device__ inline uint f2b1(float a) {
    union { float f; uint u; } v; v.f = a;
    return (v.u + 0x7fffu + ((v.u >> 16) & 1u)) >> 16;   // RNE f32->bf16
}
__device__ inline uint f2b_pk(float a, float b) { return f2b1(a) | (f2b1(b) << 16); }

// hT2 layout: el = ((b*32 + (j>>5))*512 + hd)*32 + (j&31)  -- j-tile-blocked, hd-major
// Wc layout:  el = (((nc*64 + kblk)*8 + nt)*16 + n15)*8 + k7

// ============ Kernel 0: pre-swizzle W into fragment-major bf16 (W only) ============
// Grid 64: kblk = bi, LDS-transposed. X conversion is fused into gemm_xw.
__global__ __launch_bounds__(256) void conv_w(const float* __restrict__ Wm,
                                              ushort* __restrict__ Wc) {
    __shared__ float tile[8 * 520];   // [k7][n], pitch 520
    const int kb = blockIdx.x, tid = threadIdx.x;
    const int l = tid & 63, wv = tid >> 6;
    const int col0 = l * 8;
    #pragma unroll
    for (int rsel = 0; rsel < 2; ++rsel) {
        int kr = wv + rsel * 4;
        const float4* wp = (const float4*)(Wm + (size_t)(kb * 8 + kr) * Ff + col0);
        float4 a = wp[0], c = wp[1];
        *(float4*)(&tile[kr * 520 + col0]) = a;
        *(float4*)(&tile[kr * 520 + col0 + 4]) = c;
    }
    __syncthreads();
    #pragma unroll
    for (int rsel = 0; rsel < 2; ++rsel) {
        int n = tid + rsel * 256;
        float v[8];
        #pragma unroll
        for (int u = 0; u < 8; ++u) v[u] = tile[u * 520 + n];
        uint4 o = { f2b_pk(v[0], v[1]), f2b_pk(v[2], v[3]),
                    f2b_pk(v[4], v[5]), f2b_pk(v[6], v[7]) };
        int nc = n >> 7, nt = (n >> 4) & 7, n15 = n & 15;
        *(uint4*)(Wc + ((size_t)(((nc * 64 + kb) * 8 + nt) * 16 + n15) << 3)) = o;
    }
}

// ============ Kernel 1: GEMM hT2 = (x@W)^T + exact e_i/e_j ============
// Grid 512: b = idx&7, mi = (idx>>3)&15, nc = idx>>7. 2 blocks/CU.
// A: direct f32 X load + in-register bf16 pack, reg prefetch depth 2.
// B: per-step 8 KB Wc slice staged once per block into LDS, double-buffered.
__global__ __launch_bounds__(256, 2) void gemm_xw(const float* __restrict__ X,
                                                  const ushort* __restrict__ Wc,
                                                  const float* __restrict__ a_src,
                                                  const float* __restrict__ a_dst,
                                                  ushort* __restrict__ hT,
                                                  float* __restrict__ ei,
                                                  float* __restrict__ ej) {
    __shared__ ushort Bs[2][4096];    // 2 x 8 KB K-step slices
    const int idx = blockIdx.x;
    const int b = idx & 7, sub = idx >> 3;
    const int mi = sub & 15, nc = sub >> 4;
    const int tid = threadIdx.x;
    const int w = tid >> 6, lane = tid & 63, quad = lane >> 4, l16 = lane & 15;
    const int mtile = (b * 16 + mi) * 4 + w;

    f32x4 z = {0.f, 0.f, 0.f, 0.f};
    f32x4 acc[8];
    #pragma unroll
    for (int nt = 0; nt < 8; ++nt) acc[nt] = z;

    const float* ap = X + (size_t)(mtile * 16 + l16) * Ff + quad * 8;
    const ushort* wsrc = Wc + ((size_t)nc << 16) + tid * 16;   // this thread's 32B stage slot
    const int brd = quad * 1024 + l16 * 8;                     // per-lane LDS read base

#define LOADA(s, dst) { \
        float4 f0_ = *(const float4*)(ap + (s) * 32); \
        float4 f1_ = *(const float4*)(ap + (s) * 32 + 4); \
        union { uint4 u; bf16x8 v; } o_; \
        o_.u.x = f2b_pk(f0_.x, f0_.y); o_.u.y = f2b_pk(f0_.z, f0_.w); \
        o_.u.z = f2b_pk(f1_.x, f1_.y); o_.u.w = f2b_pk(f1_.z, f1_.w); \
        dst = o_.v; }

    bf16x8 ab[2];
    bf16x8 br0, br1;

    // prologue: A depth-2 prefetch; stage B step 0
    LOADA(0, ab[0]);
    LOADA(1, ab[1]);
    br0 = *(const bf16x8*)(wsrc);
    br1 = *(const bf16x8*)(wsrc + 8);
    *(bf16x8*)(&Bs[0][tid * 16]) = br0;
    *(bf16x8*)(&Bs[0][tid * 16 + 8]) = br1;
    __syncthreads();

    #pragma unroll 2
    for (int s = 0; s < 16; ++s) {
        const int c = s & 1;
        if (s + 1 < 16) {   // issue next step's global B loads early (latency under MFMA)
            br0 = *(const bf16x8*)(wsrc + (s + 1) * 4096);
            br1 = *(const bf16x8*)(wsrc + (s + 1) * 4096 + 8);
        }
        #pragma unroll
        for (int nt = 0; nt < 8; ++nt) {
            bf16x8 bf = *(const bf16x8*)(&Bs[c][brd + nt * 128]);
            acc[nt] = __builtin_amdgcn_mfma_f32_16x16x32_bf16(ab[c], bf, acc[nt], 0, 0, 0);
        }
        if (s + 2 < 16) LOADA(s + 2, ab[c]);
        if (s + 1 < 16) {   // write next buffer (consumed two steps ago, reads drained at barrier)
            *(bf16x8*)(&Bs[(s + 1) & 1][tid * 16]) = br0;
            *(bf16x8*)(&Bs[(s + 1) & 1][tid * 16 + 8]) = br1;
        }
        __syncthreads();
    }
#undef LOADA

    // epilogue 1: hT2 store
    const int nseq = (mi * 4 + w) * 16 + quad * 4;
    const int jb = nseq >> 5, js = nseq & 31;
    #pragma unroll
    for (int nt = 0; nt < 8; ++nt) {
        uint2 pv;
        pv.x = f2b_pk(acc[nt][0], acc[nt][1]);
        pv.y = f2b_pk(acc[nt][2], acc[nt][3]);
        int hd = nc * 128 + nt * 16 + l16;
        *(uint2*)(hT + ((size_t)(b * 32 + jb)) * 16384 + (size_t)hd * 32 + js) = pv;
    }

    // epilogue 2: exact e_i/e_j (full head in this block), no atomics.
    // a_src/a_dst pre-scaled by log2(e) so attn can use exp2 directly.
    {
        float as4[8], ad4[8];
        #pragma unroll
        for (int nt = 0; nt < 8; ++nt) {
            as4[nt] = a_src[nc * 128 + nt * 16 + l16] * LOG2E;
            ad4[nt] = a_dst[nc * 128 + nt * 16 + l16] * LOG2E;
        }
        #pragma unroll
        for (int rr = 0; rr < 4; ++rr) {
            float v1 = 0.f, v2 = 0.f;
            #pragma unroll
            for (int nt = 0; nt < 8; ++nt) {
                v1 += acc[nt][rr] * as4[nt];
                v2 += acc[nt][rr] * ad4[nt];
            }
            #pragma unroll
            for (int off = 1; off < 16; off <<= 1) {
                v1 += __shfl_xor(v1, off);
                v2 += __shfl_xor(v2, off);
            }
            if (l16 == 0) {
                int n = nseq + rr;
                ei[((b * 4 + nc) << 10) + n] = v1;
                ej[((b * 4 + nc) << 10) + n] = v2;
            }
        }
    }
}

// ============ Kernel 2: attention + PV MFMA + residual + LayerNorm ============
// CHANGED: 16 i-rows/block (was 32), grid 512 (was 256) -> all 256 CUs busy
// (2 blocks/CU x 512 blocks; before, 256 blocks filled only 128 CUs).
// 512 thr = 8 waves: head w&3, j-half w>>2. acc[8] (was acc[2][8]), s_ep 33 KB.
__global__ __launch_bounds__(512, 2) void attn_pv(const ushort* __restrict__ hT,
                                                  const float* __restrict__ ei_g,
                                                  const float* __restrict__ ej_g,
                                                  const int* __restrict__ mask,
                                                  const float* __restrict__ X,
                                                  const float* __restrict__ gamma,
                                                  const float* __restrict__ beta,
                                                  float* __restrict__ out) {
    __shared__ float s_ep[16 * 516];
    __shared__ float s_as[4][16];

    const int idx = blockIdx.x;
    const int b = idx & 7, i0 = (idx >> 3) * 16;
    const int tid = threadIdx.x;
    const int w = tid >> 6, w4 = w & 3, jh = w >> 2;
    const int lane = tid & 63, quad = lane >> 4, l16 = lane & 15;

    const float* ejh = ej_g + ((b * 4 + w4) << 10);
    const int* mkb = mask + (b << 10);

    float maxej = -3.0e38f;
    #pragma unroll
    for (int k = 0; k < 16; ++k) maxej = fmaxf(maxej, ejh[lane + 64 * k]);
    #pragma unroll
    for (int off = 1; off < 64; off <<= 1) maxej = fmaxf(maxej, __shfl_xor(maxej, off));

    const float ei0 = ei_g[((b * 4 + w4) << 10) + i0 + l16];
    const int mi0 = mkb[i0 + l16];
    float m0;
    { float t = ei0 + maxej; m0 = mi0 ? fmaxf(t, 0.2f * t) : -1e9f; }

    f32x4 z = {0.f, 0.f, 0.f, 0.f};
    f32x4 acc[8], asum = z;
    #pragma unroll
    for (int dt = 0; dt < 8; ++dt) acc[dt] = z;
    bf16x8 ones;
    #pragma unroll
    for (int q = 0; q < 8; ++q) ones[q] = (short)0x3F80;

    const ushort* hTb = hT + ((size_t)(b * 32)) * 16384 + (size_t)(w4 * 128) * 32
                        + l16 * 32 + quad * 8;

    // prefetch steps 0 and 1
    bf16x8 B[2][8];
    #pragma unroll
    for (int c = 0; c < 2; ++c) {
        const ushort* h0 = hTb + (size_t)(jh * 16 + c) * 16384;
        #pragma unroll
        for (int dt = 0; dt < 8; ++dt) B[c][dt] = *(const bf16x8*)(h0 + dt * 512);
    }

    #pragma unroll 2
    for (int r = 0; r < 16; ++r) {
        const int c = r & 1;
        const int jq = (jh * 16 + r) * 32 + quad * 8;
        float4 e0 = *(const float4*)(ejh + jq);
        float4 e1 = *(const float4*)(ejh + jq + 4);
        int4 q0 = *(const int4*)(mkb + jq);
        int4 q1 = *(const int4*)(mkb + jq + 4);
        float ev[8] = {e0.x, e0.y, e0.z, e0.w, e1.x, e1.y, e1.z, e1.w};
        int   mv[8] = {q0.x, q0.y, q0.z, q0.w, q1.x, q1.y, q1.z, q1.w};
        float wv0[8];
        #pragma unroll
        for (int u = 0; u < 8; ++u) {
            float t0 = ei0 + ev[u];
            float l0 = fmaxf(t0, 0.2f * t0);
            wv0[u] = __builtin_amdgcn_exp2f(((mi0 && mv[u]) ? l0 : -1e9f) - m0);
        }
        union { uint4 u; bf16x8 v; } af0;
        af0.u.x = f2b_pk(wv0[0], wv0[1]); af0.u.y = f2b_pk(wv0[2], wv0[3]);
        af0.u.z = f2b_pk(wv0[4], wv0[5]); af0.u.w = f2b_pk(wv0[6], wv0[7]);
        asum = __builtin_amdgcn_mfma_f32_16x16x32_bf16(af0.v, ones, asum, 0, 0, 0);
        #pragma unroll
        for (int dt = 0; dt < 8; ++dt)
            acc[dt] = __builtin_amdgcn_mfma_f32_16x16x32_bf16(af0.v, B[c][dt], acc[dt], 0, 0, 0);
        if (r + 2 < 16) {   // reload slot c for step r+2
            const ushort* hn = hTb + (size_t)(jh * 16 + r + 2) * 16384;
            #pragma unroll
            for (int dt = 0; dt < 8; ++dt) B[c][dt] = *(const bf16x8*)(hn + dt * 512);
        }
    }

    if (jh == 1) {
        #pragma unroll
        for (int dt = 0; dt < 8; ++dt)
            #pragma unroll
            for (int rr = 0; rr < 4; ++rr)
                s_ep[(quad * 4 + rr) * 516 + w4 * 128 + dt * 16 + l16] = acc[dt][rr];
        if (l16 == 0) {
            #pragma unroll
            for (int rr = 0; rr < 4; ++rr)
                s_as[w4][quad * 4 + rr] = asum[rr];
        }
    }
    __syncthreads();
    if (jh == 0) {
        float rs[4];
        #pragma unroll
        for (int rr = 0; rr < 4; ++rr)
            rs[rr] = 1.f / (asum[rr] + s_as[w4][quad * 4 + rr]);
        #pragma unroll
        for (int dt = 0; dt < 8; ++dt)
            #pragma unroll
            for (int rr = 0; rr < 4; ++rr) {
                int off = (quad * 4 + rr) * 516 + w4 * 128 + dt * 16 + l16;
                s_ep[off] = (acc[dt][rr] + s_ep[off]) * rs[rr];
            }
    }
    __syncthreads();

    #pragma unroll
    for (int q = 0; q < 2; ++q) {
        int ir = w * 2 + q;
        int ig = i0 + ir;
        float4 p0 = *(const float4*)(&s_ep[ir * 516 + lane * 8]);
        float4 p1 = *(const float4*)(&s_ep[ir * 516 + lane * 8 + 4]);
        const float* xp = X + (((size_t)((b << 10) + ig)) << 9) + lane * 8;
        float4 x0 = *(const float4*)(xp);
        float4 x1 = *(const float4*)(xp + 4);
        float v[8] = {p0.x + x0.x, p0.y + x0.y, p0.z + x0.z, p0.w + x0.w,
                      p1.x + x1.x, p1.y + x1.y, p1.z + x1.z, p1.w + x1.w};
        float s1 = 0.f, s2 = 0.f;
        #pragma unroll
        for (int u = 0; u < 8; ++u) { s1 += v[u]; s2 += v[u] * v[u]; }
        #pragma unroll
        for (int off = 1; off < 64; off <<= 1) { s1 += __shfl_xor(s1, off); s2 += __shfl_xor(s2, off); }
        float mean = s1 * (1.f / 512.f);
        float var  = s2 * (1.f / 512.f) - mean * mean;
        float rstd = rsqrtf(var + 1e-5f);
        int f0i = lane * 8;
        float4 g0 = *(const float4*)(gamma + f0i);
        float4 g1 = *(const float4*)(gamma + f0i + 4);
        float4 be0 = *(const float4*)(beta + f0i);
        float4 be1 = *(const float4*)(beta + f0i + 4);
        float* op = out + (((size_t)((b << 10) + ig)) << 9) + f0i;
        float4 o0, o1;
        o0.x = (v[0] - mean) * rstd * g0.x + be0.x;
        o0.y = (v[1] - mean) * rstd * g0.y + be0.y;
        o0.z = (v[2] - mean) * rstd * g0.z + be0.z;
        o0.w = (v[3] - mean) * rstd * g0.w + be0.w;
        o1.x = (v[4] - mean) * rstd * g1.x + be1.x;
        o1.y = (v[5] - mean) * rstd * g1.y + be1.y;
        o1.z = (v[6] - mean) * rstd * g1.z + be1.z;
        o1.w = (v[7] - mean) * rstd * g1.w + be1.w;
        *(float4*)op = o0;
        *(float4*)(op + 4) = o1;
    }
}

extern "C" void kernel_launch(void* const* d_in, const int* in_sizes, int n_in,
                              void* d_out, int out_size, void* d_ws, size_t ws_size,
                              hipStream_t stream) {
    const float* x     = (const float*)d_in[0];
    const int*   mask  = (const int*)d_in[1];
    const float* W     = (const float*)d_in[2];
    const float* a_src = (const float*)d_in[3];
    const float* a_dst = (const float*)d_in[4];
    const float* gamma = (const float*)d_in[5];
    const float* beta  = (const float*)d_in[6];
    float* out = (float*)d_out;

    ushort* hT = (ushort*)d_ws;                            // 8 MB
    ushort* Wc = hT + (size_t)8 * 512 * 1024;              // 0.5 MB
    float* ei = (float*)(Wc + (size_t)512 * 512);          // 128 KB
    float* ej = ei + 32768;                                // 128 KB

    conv_w<<<dim3(64), 256, 0, stream>>>(W, Wc);
    gemm_xw<<<dim3(512), 256, 0, stream>>>(x, Wc, a_src, a_dst, hT, ei, ej);
    attn_pv<<<dim3(512), 512, 0, stream>>>(hT, ei, ej, mask, x, gamma, beta, out);
}

// Round 16
// 126.333 us; speedup vs baseline: 1.1056x; 1.1056x over previous
//
#include <hip/hip_runtime.h>
#include <math.h>

#define Bsz 8
#define Nn 1024
#define Ff 512
#define Hh 4
#define Dd 128

typedef float f32x4 __attribute__((ext_vector_type(4)));
typedef short bf16x8 __attribute__((ext_vector_type(8)));

#define LOG2E 1.44269504f

__device__ inline uint f2b1(float a) {
    union { float f; uint u; } v; v.f = a;
    return (v.u + 0x7fffu + ((v.u >> 16) & 1u)) >> 16;   // RNE f32->bf16
}
__device__ inline uint f2b_pk(float a, float b) { return f2b1(a) | (f2b1(b) << 16); }

// hT2 layout: el = ((b*32 + (j>>5))*512 + hd)*32 + (j&31)  -- j-tile-blocked, hd-major
// Wc layout:  el = (((nc*64 + kblk)*8 + nt)*16 + n15)*8 + k7

// ============ Kernel 0: pre-swizzle W into fragment-major bf16 (W only) ============
__global__ __launch_bounds__(256) void conv_w(const float* __restrict__ Wm,
                                              ushort* __restrict__ Wc) {
    __shared__ float tile[8 * 520];   // [k7][n], pitch 520
    const int kb = blockIdx.x, tid = threadIdx.x;
    const int l = tid & 63, wv = tid >> 6;
    const int col0 = l * 8;
    #pragma unroll
    for (int rsel = 0; rsel < 2; ++rsel) {
        int kr = wv + rsel * 4;
        const float4* wp = (const float4*)(Wm + (size_t)(kb * 8 + kr) * Ff + col0);
        float4 a = wp[0], c = wp[1];
        *(float4*)(&tile[kr * 520 + col0]) = a;
        *(float4*)(&tile[kr * 520 + col0 + 4]) = c;
    }
    __syncthreads();
    #pragma unroll
    for (int rsel = 0; rsel < 2; ++rsel) {
        int n = tid + rsel * 256;
        float v[8];
        #pragma unroll
        for (int u = 0; u < 8; ++u) v[u] = tile[u * 520 + n];
        uint4 o = { f2b_pk(v[0], v[1]), f2b_pk(v[2], v[3]),
                    f2b_pk(v[4], v[5]), f2b_pk(v[6], v[7]) };
        int nc = n >> 7, nt = (n >> 4) & 7, n15 = n & 15;
        *(uint4*)(Wc + ((size_t)(((nc * 64 + kb) * 8 + nt) * 16 + n15) << 3)) = o;
    }
}

// ============ Kernel 1: GEMM hT2 = (x@W)^T + exact e_i/e_j ============
// Grid 512. A: f32 X direct + in-reg bf16 pack. B: LDS-staged, double-buffered.
// 16-step loop fully unrolled via macro with LITERAL step numbers;
// ab[2] -> named ab0/ab1 (runtime-parity reg-array index risks scratch demotion,
// rule #20 — attn's VGPR=76 proved it happened there).
__global__ __launch_bounds__(256, 2) void gemm_xw(const float* __restrict__ X,
                                                  const ushort* __restrict__ Wc,
                                                  const float* __restrict__ a_src,
                                                  const float* __restrict__ a_dst,
                                                  ushort* __restrict__ hT,
                                                  float* __restrict__ ei,
                                                  float* __restrict__ ej) {
    __shared__ ushort Bs[2][4096];    // 2 x 8 KB K-step slices
    const int idx = blockIdx.x;
    const int b = idx & 7, sub = idx >> 3;
    const int mi = sub & 15, nc = sub >> 4;
    const int tid = threadIdx.x;
    const int w = tid >> 6, lane = tid & 63, quad = lane >> 4, l16 = lane & 15;
    const int mtile = (b * 16 + mi) * 4 + w;

    f32x4 z = {0.f, 0.f, 0.f, 0.f};
    f32x4 acc[8];
    #pragma unroll
    for (int nt = 0; nt < 8; ++nt) acc[nt] = z;

    const float* ap = X + (size_t)(mtile * 16 + l16) * Ff + quad * 8;
    const ushort* wsrc = Wc + ((size_t)nc << 16) + tid * 16;   // this thread's 32B stage slot
    const int brd = quad * 1024 + l16 * 8;                     // per-lane LDS read base

#define LOADA(s, dst) { \
        float4 f0_ = *(const float4*)(ap + (s) * 32); \
        float4 f1_ = *(const float4*)(ap + (s) * 32 + 4); \
        union { uint4 u; bf16x8 v; } o_; \
        o_.u.x = f2b_pk(f0_.x, f0_.y); o_.u.y = f2b_pk(f0_.z, f0_.w); \
        o_.u.z = f2b_pk(f1_.x, f1_.y); o_.u.w = f2b_pk(f1_.z, f1_.w); \
        dst = o_.v; }

    bf16x8 ab0, ab1;
    bf16x8 br0, br1;

    // prologue: A depth-2 prefetch; stage B step 0
    LOADA(0, ab0);
    LOADA(1, ab1);
    br0 = *(const bf16x8*)(wsrc);
    br1 = *(const bf16x8*)(wsrc + 8);
    *(bf16x8*)(&Bs[0][tid * 16]) = br0;
    *(bf16x8*)(&Bs[0][tid * 16 + 8]) = br1;
    __syncthreads();

#define GEMM_STEP(S, ABc) { \
    if ((S) + 1 < 16) { \
        br0 = *(const bf16x8*)(wsrc + ((S) + 1) * 4096); \
        br1 = *(const bf16x8*)(wsrc + ((S) + 1) * 4096 + 8); \
    } \
    _Pragma("unroll") \
    for (int nt = 0; nt < 8; ++nt) { \
        bf16x8 bf = *(const bf16x8*)(&Bs[(S) & 1][brd + nt * 128]); \
        acc[nt] = __builtin_amdgcn_mfma_f32_16x16x32_bf16(ABc, bf, acc[nt], 0, 0, 0); \
    } \
    if ((S) + 2 < 16) LOADA((S) + 2, ABc); \
    if ((S) + 1 < 16) { \
        *(bf16x8*)(&Bs[((S) + 1) & 1][tid * 16]) = br0; \
        *(bf16x8*)(&Bs[((S) + 1) & 1][tid * 16 + 8]) = br1; \
    } \
    __syncthreads(); \
}

    GEMM_STEP(0, ab0)   GEMM_STEP(1, ab1)
    GEMM_STEP(2, ab0)   GEMM_STEP(3, ab1)
    GEMM_STEP(4, ab0)   GEMM_STEP(5, ab1)
    GEMM_STEP(6, ab0)   GEMM_STEP(7, ab1)
    GEMM_STEP(8, ab0)   GEMM_STEP(9, ab1)
    GEMM_STEP(10, ab0)  GEMM_STEP(11, ab1)
    GEMM_STEP(12, ab0)  GEMM_STEP(13, ab1)
    GEMM_STEP(14, ab0)  GEMM_STEP(15, ab1)
#undef GEMM_STEP
#undef LOADA

    // epilogue 1: hT2 store
    const int nseq = (mi * 4 + w) * 16 + quad * 4;
    const int jb = nseq >> 5, js = nseq & 31;
    #pragma unroll
    for (int nt = 0; nt < 8; ++nt) {
        uint2 pv;
        pv.x = f2b_pk(acc[nt][0], acc[nt][1]);
        pv.y = f2b_pk(acc[nt][2], acc[nt][3]);
        int hd = nc * 128 + nt * 16 + l16;
        *(uint2*)(hT + ((size_t)(b * 32 + jb)) * 16384 + (size_t)hd * 32 + js) = pv;
    }

    // epilogue 2: exact e_i/e_j; a_src/a_dst pre-scaled by log2(e) for exp2.
    {
        float as4[8], ad4[8];
        #pragma unroll
        for (int nt = 0; nt < 8; ++nt) {
            as4[nt] = a_src[nc * 128 + nt * 16 + l16] * LOG2E;
            ad4[nt] = a_dst[nc * 128 + nt * 16 + l16] * LOG2E;
        }
        #pragma unroll
        for (int rr = 0; rr < 4; ++rr) {
            float v1 = 0.f, v2 = 0.f;
            #pragma unroll
            for (int nt = 0; nt < 8; ++nt) {
                v1 += acc[nt][rr] * as4[nt];
                v2 += acc[nt][rr] * ad4[nt];
            }
            #pragma unroll
            for (int off = 1; off < 16; off <<= 1) {
                v1 += __shfl_xor(v1, off);
                v2 += __shfl_xor(v2, off);
            }
            if (l16 == 0) {
                int n = nseq + rr;
                ei[((b * 4 + nc) << 10) + n] = v1;
                ej[((b * 4 + nc) << 10) + n] = v2;
            }
        }
    }
}

// ============ Kernel 2: attention + PV MFMA + residual + LayerNorm ============
// 32 i-rows/block, grid 256 (R13's 16-row split regressed +15 us).
// B[2][8] -> named B0[8]/B1[8]; acc[2][8] -> acc0/acc1; 16-step loop
// fully unrolled with literal step numbers. R13 counters showed VGPR=76 (< the
// 130+ live state) + all-pipes-idle: B[] had been demoted to scratch (rule #20).
__global__ __launch_bounds__(512, 2) void attn_pv(const ushort* __restrict__ hT,
                                                  const float* __restrict__ ei_g,
                                                  const float* __restrict__ ej_g,
                                                  const int* __restrict__ mask,
                                                  const float* __restrict__ X,
                                                  const float* __restrict__ gamma,
                                                  const float* __restrict__ beta,
                                                  float* __restrict__ out) {
    __shared__ float s_ep[32 * 516];
    __shared__ float s_as[4][32];

    const int idx = blockIdx.x;
    const int b = idx & 7, i0 = (idx >> 3) * 32;
    const int tid = threadIdx.x;
    const int w = tid >> 6, w4 = w & 3, jh = w >> 2;
    const int lane = tid & 63, quad = lane >> 4, l16 = lane & 15;

    const float* ejh = ej_g + ((b * 4 + w4) << 10);
    const int* mkb = mask + (b << 10);

    float maxej = -3.0e38f;
    #pragma unroll
    for (int k = 0; k < 16; ++k) maxej = fmaxf(maxej, ejh[lane + 64 * k]);
    #pragma unroll
    for (int off = 1; off < 64; off <<= 1) maxej = fmaxf(maxej, __shfl_xor(maxej, off));

    const float ei0 = ei_g[((b * 4 + w4) << 10) + i0 + l16];
    const float ei1 = ei_g[((b * 4 + w4) << 10) + i0 + 16 + l16];
    const int mi0 = mkb[i0 + l16];
    const int mi1 = mkb[i0 + 16 + l16];
    float m0, m1;
    { float t = ei0 + maxej; m0 = mi0 ? fmaxf(t, 0.2f * t) : -1e9f; }
    { float t = ei1 + maxej; m1 = mi1 ? fmaxf(t, 0.2f * t) : -1e9f; }

    f32x4 z = {0.f, 0.f, 0.f, 0.f};
    f32x4 acc0[8], acc1[8], asum0 = z, asum1 = z;
    #pragma unroll
    for (int dt = 0; dt < 8; ++dt) { acc0[dt] = z; acc1[dt] = z; }
    bf16x8 ones;
    #pragma unroll
    for (int q = 0; q < 8; ++q) ones[q] = (short)0x3F80;

    const ushort* hTb = hT + ((size_t)(b * 32)) * 16384 + (size_t)(w4 * 128) * 32
                        + l16 * 32 + quad * 8;

    // prefetch steps 0 and 1 into NAMED buffers
    bf16x8 B0[8], B1[8];
    {
        const ushort* h0 = hTb + (size_t)(jh * 16 + 0) * 16384;
        #pragma unroll
        for (int dt = 0; dt < 8; ++dt) B0[dt] = *(const bf16x8*)(h0 + dt * 512);
        const ushort* h1 = hTb + (size_t)(jh * 16 + 1) * 16384;
        #pragma unroll
        for (int dt = 0; dt < 8; ++dt) B1[dt] = *(const bf16x8*)(h1 + dt * 512);
    }

#define ATTN_STEP(R, BC) { \
    const int jq = (jh * 16 + (R)) * 32 + quad * 8; \
    float4 e0 = *(const float4*)(ejh + jq); \
    float4 e1 = *(const float4*)(ejh + jq + 4); \
    int4 q0 = *(const int4*)(mkb + jq); \
    int4 q1 = *(const int4*)(mkb + jq + 4); \
    float ev[8] = {e0.x, e0.y, e0.z, e0.w, e1.x, e1.y, e1.z, e1.w}; \
    int   mv[8] = {q0.x, q0.y, q0.z, q0.w, q1.x, q1.y, q1.z, q1.w}; \
    float wv0[8], wv1[8]; \
    _Pragma("unroll") \
    for (int u = 0; u < 8; ++u) { \
        float t0 = ei0 + ev[u]; \
        float l0 = fmaxf(t0, 0.2f * t0); \
        wv0[u] = __builtin_amdgcn_exp2f(((mi0 && mv[u]) ? l0 : -1e9f) - m0); \
        float t1 = ei1 + ev[u]; \
        float l1 = fmaxf(t1, 0.2f * t1); \
        wv1[u] = __builtin_amdgcn_exp2f(((mi1 && mv[u]) ? l1 : -1e9f) - m1); \
    } \
    union { uint4 u; bf16x8 v; } af0, af1; \
    af0.u.x = f2b_pk(wv0[0], wv0[1]); af0.u.y = f2b_pk(wv0[2], wv0[3]); \
    af0.u.z = f2b_pk(wv0[4], wv0[5]); af0.u.w = f2b_pk(wv0[6], wv0[7]); \
    af1.u.x = f2b_pk(wv1[0], wv1[1]); af1.u.y = f2b_pk(wv1[2], wv1[3]); \
    af1.u.z = f2b_pk(wv1[4], wv1[5]); af1.u.w = f2b_pk(wv1[6], wv1[7]); \
    asum0 = __builtin_amdgcn_mfma_f32_16x16x32_bf16(af0.v, ones, asum0, 0, 0, 0); \
    asum1 = __builtin_amdgcn_mfma_f32_16x16x32_bf16(af1.v, ones, asum1, 0, 0, 0); \
    _Pragma("unroll") \
    for (int dt = 0; dt < 8; ++dt) { \
        acc0[dt] = __builtin_amdgcn_mfma_f32_16x16x32_bf16(af0.v, BC[dt], acc0[dt], 0, 0, 0); \
        acc1[dt] = __builtin_amdgcn_mfma_f32_16x16x32_bf16(af1.v, BC[dt], acc1[dt], 0, 0, 0); \
    } \
    if ((R) + 2 < 16) { \
        const ushort* hn = hTb + (size_t)(jh * 16 + (R) + 2) * 16384; \
        _Pragma("unroll") \
        for (int dt = 0; dt < 8; ++dt) BC[dt] = *(const bf16x8*)(hn + dt * 512); \
    } \
}

    ATTN_STEP(0, B0)   ATTN_STEP(1, B1)
    ATTN_STEP(2, B0)   ATTN_STEP(3, B1)
    ATTN_STEP(4, B0)   ATTN_STEP(5, B1)
    ATTN_STEP(6, B0)   ATTN_STEP(7, B1)
    ATTN_STEP(8, B0)   ATTN_STEP(9, B1)
    ATTN_STEP(10, B0)  ATTN_STEP(11, B1)
    ATTN_STEP(12, B0)  ATTN_STEP(13, B1)
    ATTN_STEP(14, B0)  ATTN_STEP(15, B1)
#undef ATTN_STEP

    if (jh == 1) {
        #pragma unroll
        for (int dt = 0; dt < 8; ++dt)
            #pragma unroll
            for (int rr = 0; rr < 4; ++rr) {
                s_ep[(quad * 4 + rr) * 516 + w4 * 128 + dt * 16 + l16] = acc0[dt][rr];
                s_ep[(16 + quad * 4 + rr) * 516 + w4 * 128 + dt * 16 + l16] = acc1[dt][rr];
            }
        if (l16 == 0) {
            #pragma unroll
            for (int rr = 0; rr < 4; ++rr) {
                s_as[w4][quad * 4 + rr] = asum0[rr];
                s_as[w4][16 + quad * 4 + rr] = asum1[rr];
            }
        }
    }
    __syncthreads();
    if (jh == 0) {
        float rs0[4], rs1[4];
        #pragma unroll
        for (int rr = 0; rr < 4; ++rr) {
            rs0[rr] = 1.f / (asum0[rr] + s_as[w4][quad * 4 + rr]);
            rs1[rr] = 1.f / (asum1[rr] + s_as[w4][16 + quad * 4 + rr]);
        }
        #pragma unroll
        for (int dt = 0; dt < 8; ++dt)
            #pragma unroll
            for (int rr = 0; rr < 4; ++rr) {
                int off0 = (quad * 4 + rr) * 516 + w4 * 128 + dt * 16 + l16;
                s_ep[off0] = (acc0[dt][rr] + s_ep[off0]) * rs0[rr];
                int off1 = (16 + quad * 4 + rr) * 516 + w4 * 128 + dt * 16 + l16;
                s_ep[off1] = (acc1[dt][rr] + s_ep[off1]) * rs1[rr];
            }
    }
    __syncthreads();

    #pragma unroll
    for (int q = 0; q < 4; ++q) {
        int ir = w * 4 + q;
        int ig = i0 + ir;
        float4 p0 = *(const float4*)(&s_ep[ir * 516 + lane * 8]);
        float4 p1 = *(const float4*)(&s_ep[ir * 516 + lane * 8 + 4]);
        const float* xp = X + (((size_t)((b << 10) + ig)) << 9) + lane * 8;
        float4 x0 = *(const float4*)(xp);
        float4 x1 = *(const float4*)(xp + 4);
        float v[8] = {p0.x + x0.x, p0.y + x0.y, p0.z + x0.z, p0.w + x0.w,
                      p1.x + x1.x, p1.y + x1.y, p1.z + x1.z, p1.w + x1.w};
        float s1 = 0.f, s2 = 0.f;
        #pragma unroll
        for (int u = 0; u < 8; ++u) { s1 += v[u]; s2 += v[u] * v[u]; }
        #pragma unroll
        for (int off = 1; off < 64; off <<= 1) { s1 += __shfl_xor(s1, off); s2 += __shfl_xor(s2, off); }
        float mean = s1 * (1.f / 512.f);
        float var  = s2 * (1.f / 512.f) - mean * mean;
        float rstd = rsqrtf(var + 1e-5f);
        int f0i = lane * 8;
        float4 g0 = *(const float4*)(gamma + f0i);
        float4 g1 = *(const float4*)(gamma + f0i + 4);
        float4 be0 = *(const float4*)(beta + f0i);
        float4 be1 = *(const float4*)(beta + f0i + 4);
        float* op = out + (((size_t)((b << 10) + ig)) << 9) + f0i;
        float4 o0, o1;
        o0.x = (v[0] - mean) * rstd * g0.x + be0.x;
        o0.y = (v[1] - mean) * rstd * g0.y + be0.y;
        o0.z = (v[2] - mean) * rstd * g0.z + be0.z;
        o0.w = (v[3] - mean) * rstd * g0.w + be0.w;
        o1.x = (v[4] - mean) * rstd * g1.x + be1.x;
        o1.y = (v[5] - mean) * rstd * g1.y + be1.y;
        o1.z = (v[6] - mean) * rstd * g1.z + be1.z;
        o1.w = (v[7] - mean) * rstd * g1.w + be1.w;
        *(float4*)op = o0;
        *(float4*)(op + 4) = o1;
    }
}

extern "C" void kernel_launch(void* const* d_in, const int* in_sizes, int n_in,
                              void* d_out, int out_size, void* d_ws, size_t ws_size,
                              hipStream_t stream) {
    const float* x     = (const float*)d_in[0];
    const int*   mask  = (const int*)d_in[1];
    const float* W     = (const float*)d_in[2];
    const float* a_src = (const float*)d_in[3];
    const float* a_dst = (const float*)d_in[4];
    const float* gamma = (const float*)d_in[5];
    const float* beta  = (const float*)d_in[6];
    float* out = (float*)d_out;

    ushort* hT = (ushort*)d_ws;                            // 8 MB
    ushort* Wc = hT + (size_t)8 * 512 * 1024;              // 0.5 MB
    float* ei = (float*)(Wc + (size_t)512 * 512);          // 128 KB
    float* ej = ei + 32768;                                // 128 KB

    conv_w<<<dim3(64), 256, 0, stream>>>(W, Wc);
    gemm_xw<<<dim3(512), 256, 0, stream>>>(x, Wc, a_src, a_dst, hT, ei, ej);
    attn_pv<<<dim3(256), 512, 0, stream>>>(hT, ei, ej, mask, x, gamma, beta, out);
}

// Round 17
// 124.929 us; speedup vs baseline: 1.1180x; 1.0112x over previous
//
#include <hip/hip_runtime.h>
#include <math.h>

#define Bsz 8
#define Nn 1024
#define Ff 512
#define Hh 4
#define Dd 128

typedef float f32x4 __attribute__((ext_vector_type(4)));
typedef short bf16x8 __attribute__((ext_vector_type(8)));

#define LOG2E 1.44269504f

__device__ inline uint f2b1(float a) {
    union { float f; uint u; } v; v.f = a;
    return (v.u + 0x7fffu + ((v.u >> 16) & 1u)) >> 16;   // RNE f32->bf16
}
__device__ inline uint f2b_pk(float a, float b) { return f2b1(a) | (f2b1(b) << 16); }

// hT2 layout: el = ((b*32 + (j>>5))*512 + hd)*32 + (j&31)  -- j-tile-blocked, hd-major
// Wc layout:  el = (((nc*64 + kblk)*8 + nt)*16 + n15)*8 + k7

// ============ Kernel 0: pre-swizzle W into fragment-major bf16 (W only) ============
__global__ __launch_bounds__(256) void conv_w(const float* __restrict__ Wm,
                                              ushort* __restrict__ Wc) {
    __shared__ float tile[8 * 520];   // [k7][n], pitch 520
    const int kb = blockIdx.x, tid = threadIdx.x;
    const int l = tid & 63, wv = tid >> 6;
    const int col0 = l * 8;
    #pragma unroll
    for (int rsel = 0; rsel < 2; ++rsel) {
        int kr = wv + rsel * 4;
        const float4* wp = (const float4*)(Wm + (size_t)(kb * 8 + kr) * Ff + col0);
        float4 a = wp[0], c = wp[1];
        *(float4*)(&tile[kr * 520 + col0]) = a;
        *(float4*)(&tile[kr * 520 + col0 + 4]) = c;
    }
    __syncthreads();
    #pragma unroll
    for (int rsel = 0; rsel < 2; ++rsel) {
        int n = tid + rsel * 256;
        float v[8];
        #pragma unroll
        for (int u = 0; u < 8; ++u) v[u] = tile[u * 520 + n];
        uint4 o = { f2b_pk(v[0], v[1]), f2b_pk(v[2], v[3]),
                    f2b_pk(v[4], v[5]), f2b_pk(v[6], v[7]) };
        int nc = n >> 7, nt = (n >> 4) & 7, n15 = n & 15;
        *(uint4*)(Wc + ((size_t)(((nc * 64 + kb) * 8 + nt) * 16 + n15) << 3)) = o;
    }
}

// ============ Kernel 1: GEMM hT2 = (x@W)^T + exact e_i/e_j ============
// KEPT from R16: fully-unrolled GEMM_STEP with literal step numbers + named
// ab0/ab1 (R16 arithmetic: gemm gained ~40 us vs the loop form — the loop
// form's ab[c] was the real scratch victim).
__global__ __launch_bounds__(256, 2) void gemm_xw(const float* __restrict__ X,
                                                  const ushort* __restrict__ Wc,
                                                  const float* __restrict__ a_src,
                                                  const float* __restrict__ a_dst,
                                                  ushort* __restrict__ hT,
                                                  float* __restrict__ ei,
                                                  float* __restrict__ ej) {
    __shared__ ushort Bs[2][4096];    // 2 x 8 KB K-step slices
    const int idx = blockIdx.x;
    const int b = idx & 7, sub = idx >> 3;
    const int mi = sub & 15, nc = sub >> 4;
    const int tid = threadIdx.x;
    const int w = tid >> 6, lane = tid & 63, quad = lane >> 4, l16 = lane & 15;
    const int mtile = (b * 16 + mi) * 4 + w;

    f32x4 z = {0.f, 0.f, 0.f, 0.f};
    f32x4 acc[8];
    #pragma unroll
    for (int nt = 0; nt < 8; ++nt) acc[nt] = z;

    const float* ap = X + (size_t)(mtile * 16 + l16) * Ff + quad * 8;
    const ushort* wsrc = Wc + ((size_t)nc << 16) + tid * 16;   // this thread's 32B stage slot
    const int brd = quad * 1024 + l16 * 8;                     // per-lane LDS read base

#define LOADA(s, dst) { \
        float4 f0_ = *(const float4*)(ap + (s) * 32); \
        float4 f1_ = *(const float4*)(ap + (s) * 32 + 4); \
        union { uint4 u; bf16x8 v; } o_; \
        o_.u.x = f2b_pk(f0_.x, f0_.y); o_.u.y = f2b_pk(f0_.z, f0_.w); \
        o_.u.z = f2b_pk(f1_.x, f1_.y); o_.u.w = f2b_pk(f1_.z, f1_.w); \
        dst = o_.v; }

    bf16x8 ab0, ab1;
    bf16x8 br0, br1;

    // prologue: A depth-2 prefetch; stage B step 0
    LOADA(0, ab0);
    LOADA(1, ab1);
    br0 = *(const bf16x8*)(wsrc);
    br1 = *(const bf16x8*)(wsrc + 8);
    *(bf16x8*)(&Bs[0][tid * 16]) = br0;
    *(bf16x8*)(&Bs[0][tid * 16 + 8]) = br1;
    __syncthreads();

#define GEMM_STEP(S, ABc) { \
    if ((S) + 1 < 16) { \
        br0 = *(const bf16x8*)(wsrc + ((S) + 1) * 4096); \
        br1 = *(const bf16x8*)(wsrc + ((S) + 1) * 4096 + 8); \
    } \
    _Pragma("unroll") \
    for (int nt = 0; nt < 8; ++nt) { \
        bf16x8 bf = *(const bf16x8*)(&Bs[(S) & 1][brd + nt * 128]); \
        acc[nt] = __builtin_amdgcn_mfma_f32_16x16x32_bf16(ABc, bf, acc[nt], 0, 0, 0); \
    } \
    if ((S) + 2 < 16) LOADA((S) + 2, ABc); \
    if ((S) + 1 < 16) { \
        *(bf16x8*)(&Bs[((S) + 1) & 1][tid * 16]) = br0; \
        *(bf16x8*)(&Bs[((S) + 1) & 1][tid * 16 + 8]) = br1; \
    } \
    __syncthreads(); \
}

    GEMM_STEP(0, ab0)   GEMM_STEP(1, ab1)
    GEMM_STEP(2, ab0)   GEMM_STEP(3, ab1)
    GEMM_STEP(4, ab0)   GEMM_STEP(5, ab1)
    GEMM_STEP(6, ab0)   GEMM_STEP(7, ab1)
    GEMM_STEP(8, ab0)   GEMM_STEP(9, ab1)
    GEMM_STEP(10, ab0)  GEMM_STEP(11, ab1)
    GEMM_STEP(12, ab0)  GEMM_STEP(13, ab1)
    GEMM_STEP(14, ab0)  GEMM_STEP(15, ab1)
#undef GEMM_STEP
#undef LOADA

    // epilogue 1: hT2 store
    const int nseq = (mi * 4 + w) * 16 + quad * 4;
    const int jb = nseq >> 5, js = nseq & 31;
    #pragma unroll
    for (int nt = 0; nt < 8; ++nt) {
        uint2 pv;
        pv.x = f2b_pk(acc[nt][0], acc[nt][1]);
        pv.y = f2b_pk(acc[nt][2], acc[nt][3]);
        int hd = nc * 128 + nt * 16 + l16;
        *(uint2*)(hT + ((size_t)(b * 32 + jb)) * 16384 + (size_t)hd * 32 + js) = pv;
    }

    // epilogue 2: exact e_i/e_j; a_src/a_dst pre-scaled by log2(e) for exp2.
    {
        float as4[8], ad4[8];
        #pragma unroll
        for (int nt = 0; nt < 8; ++nt) {
            as4[nt] = a_src[nc * 128 + nt * 16 + l16] * LOG2E;
            ad4[nt] = a_dst[nc * 128 + nt * 16 + l16] * LOG2E;
        }
        #pragma unroll
        for (int rr = 0; rr < 4; ++rr) {
            float v1 = 0.f, v2 = 0.f;
            #pragma unroll
            for (int nt = 0; nt < 8; ++nt) {
                v1 += acc[nt][rr] * as4[nt];
                v2 += acc[nt][rr] * ad4[nt];
            }
            #pragma unroll
            for (int off = 1; off < 16; off <<= 1) {
                v1 += __shfl_xor(v1, off);
                v2 += __shfl_xor(v2, off);
            }
            if (l16 == 0) {
                int n = nseq + rr;
                ei[((b * 4 + nc) << 10) + n] = v1;
                ej[((b * 4 + nc) << 10) + n] = v2;
            }
        }
    }
}

// ============ Kernel 2: attention + PV MFMA + residual + LayerNorm ============
// REVERTED to the R12 loop form (measured-best attn: <45 us). R16's full unroll
// regressed attn to ~83 us — the big step body (8 exp2 + 18 MFMA) x16 literal
// copies thrashes I-cache. Loop form with #pragma unroll 2, B[2][8], grid 256.
__global__ __launch_bounds__(512, 2) void attn_pv(const ushort* __restrict__ hT,
                                                  const float* __restrict__ ei_g,
                                                  const float* __restrict__ ej_g,
                                                  const int* __restrict__ mask,
                                                  const float* __restrict__ X,
                                                  const float* __restrict__ gamma,
                                                  const float* __restrict__ beta,
                                                  float* __restrict__ out) {
    __shared__ float s_ep[32 * 516];
    __shared__ float s_as[4][32];

    const int idx = blockIdx.x;
    const int b = idx & 7, i0 = (idx >> 3) * 32;
    const int tid = threadIdx.x;
    const int w = tid >> 6, w4 = w & 3, jh = w >> 2;
    const int lane = tid & 63, quad = lane >> 4, l16 = lane & 15;

    const float* ejh = ej_g + ((b * 4 + w4) << 10);
    const int* mkb = mask + (b << 10);

    float maxej = -3.0e38f;
    #pragma unroll
    for (int k = 0; k < 16; ++k) maxej = fmaxf(maxej, ejh[lane + 64 * k]);
    #pragma unroll
    for (int off = 1; off < 64; off <<= 1) maxej = fmaxf(maxej, __shfl_xor(maxej, off));

    const float ei0 = ei_g[((b * 4 + w4) << 10) + i0 + l16];
    const float ei1 = ei_g[((b * 4 + w4) << 10) + i0 + 16 + l16];
    const int mi0 = mkb[i0 + l16];
    const int mi1 = mkb[i0 + 16 + l16];
    float m0, m1;
    { float t = ei0 + maxej; m0 = mi0 ? fmaxf(t, 0.2f * t) : -1e9f; }
    { float t = ei1 + maxej; m1 = mi1 ? fmaxf(t, 0.2f * t) : -1e9f; }

    f32x4 z = {0.f, 0.f, 0.f, 0.f};
    f32x4 acc[2][8], asum[2];
    #pragma unroll
    for (int it = 0; it < 2; ++it) { asum[it] = z;
        #pragma unroll
        for (int dt = 0; dt < 8; ++dt) acc[it][dt] = z; }
    bf16x8 ones;
    #pragma unroll
    for (int q = 0; q < 8; ++q) ones[q] = (short)0x3F80;

    const ushort* hTb = hT + ((size_t)(b * 32)) * 16384 + (size_t)(w4 * 128) * 32
                        + l16 * 32 + quad * 8;

    // prefetch steps 0 and 1
    bf16x8 B[2][8];
    #pragma unroll
    for (int c = 0; c < 2; ++c) {
        const ushort* h0 = hTb + (size_t)(jh * 16 + c) * 16384;
        #pragma unroll
        for (int dt = 0; dt < 8; ++dt) B[c][dt] = *(const bf16x8*)(h0 + dt * 512);
    }

    #pragma unroll 2
    for (int r = 0; r < 16; ++r) {
        const int c = r & 1;
        const int jq = (jh * 16 + r) * 32 + quad * 8;
        float4 e0 = *(const float4*)(ejh + jq);
        float4 e1 = *(const float4*)(ejh + jq + 4);
        int4 q0 = *(const int4*)(mkb + jq);
        int4 q1 = *(const int4*)(mkb + jq + 4);
        float ev[8] = {e0.x, e0.y, e0.z, e0.w, e1.x, e1.y, e1.z, e1.w};
        int   mv[8] = {q0.x, q0.y, q0.z, q0.w, q1.x, q1.y, q1.z, q1.w};
        float wv0[8], wv1[8];
        #pragma unroll
        for (int u = 0; u < 8; ++u) {
            float t0 = ei0 + ev[u];
            float l0 = fmaxf(t0, 0.2f * t0);
            wv0[u] = __builtin_amdgcn_exp2f(((mi0 && mv[u]) ? l0 : -1e9f) - m0);
            float t1 = ei1 + ev[u];
            float l1 = fmaxf(t1, 0.2f * t1);
            wv1[u] = __builtin_amdgcn_exp2f(((mi1 && mv[u]) ? l1 : -1e9f) - m1);
        }
        union { uint4 u; bf16x8 v; } af0, af1;
        af0.u.x = f2b_pk(wv0[0], wv0[1]); af0.u.y = f2b_pk(wv0[2], wv0[3]);
        af0.u.z = f2b_pk(wv0[4], wv0[5]); af0.u.w = f2b_pk(wv0[6], wv0[7]);
        af1.u.x = f2b_pk(wv1[0], wv1[1]); af1.u.y = f2b_pk(wv1[2], wv1[3]);
        af1.u.z = f2b_pk(wv1[4], wv1[5]); af1.u.w = f2b_pk(wv1[6], wv1[7]);
        asum[0] = __builtin_amdgcn_mfma_f32_16x16x32_bf16(af0.v, ones, asum[0], 0, 0, 0);
        asum[1] = __builtin_amdgcn_mfma_f32_16x16x32_bf16(af1.v, ones, asum[1], 0, 0, 0);
        #pragma unroll
        for (int dt = 0; dt < 8; ++dt) {
            acc[0][dt] = __builtin_amdgcn_mfma_f32_16x16x32_bf16(af0.v, B[c][dt], acc[0][dt], 0, 0, 0);
            acc[1][dt] = __builtin_amdgcn_mfma_f32_16x16x32_bf16(af1.v, B[c][dt], acc[1][dt], 0, 0, 0);
        }
        if (r + 2 < 16) {   // reload slot c for step r+2
            const ushort* hn = hTb + (size_t)(jh * 16 + r + 2) * 16384;
            #pragma unroll
            for (int dt = 0; dt < 8; ++dt) B[c][dt] = *(const bf16x8*)(hn + dt * 512);
        }
    }

    if (jh == 1) {
        #pragma unroll
        for (int it = 0; it < 2; ++it)
            #pragma unroll
            for (int dt = 0; dt < 8; ++dt)
                #pragma unroll
                for (int rr = 0; rr < 4; ++rr)
                    s_ep[(it * 16 + quad * 4 + rr) * 516 + w4 * 128 + dt * 16 + l16] =
                        acc[it][dt][rr];
        if (l16 == 0) {
            #pragma unroll
            for (int it = 0; it < 2; ++it)
                #pragma unroll
                for (int rr = 0; rr < 4; ++rr)
                    s_as[w4][it * 16 + quad * 4 + rr] = asum[it][rr];
        }
    }
    __syncthreads();
    if (jh == 0) {
        float rs[2][4];
        #pragma unroll
        for (int it = 0; it < 2; ++it)
            #pragma unroll
            for (int rr = 0; rr < 4; ++rr)
                rs[it][rr] = 1.f / (asum[it][rr] + s_as[w4][it * 16 + quad * 4 + rr]);
        #pragma unroll
        for (int it = 0; it < 2; ++it)
            #pragma unroll
            for (int dt = 0; dt < 8; ++dt)
                #pragma unroll
                for (int rr = 0; rr < 4; ++rr) {
                    int off = (it * 16 + quad * 4 + rr) * 516 + w4 * 128 + dt * 16 + l16;
                    s_ep[off] = (acc[it][dt][rr] + s_ep[off]) * rs[it][rr];
                }
    }
    __syncthreads();

    #pragma unroll
    for (int q = 0; q < 4; ++q) {
        int ir = w * 4 + q;
        int ig = i0 + ir;
        float4 p0 = *(const float4*)(&s_ep[ir * 516 + lane * 8]);
        float4 p1 = *(const float4*)(&s_ep[ir * 516 + lane * 8 + 4]);
        const float* xp = X + (((size_t)((b << 10) + ig)) << 9) + lane * 8;
        float4 x0 = *(const float4*)(xp);
        float4 x1 = *(const float4*)(xp + 4);
        float v[8] = {p0.x + x0.x, p0.y + x0.y, p0.z + x0.z, p0.w + x0.w,
                      p1.x + x1.x, p1.y + x1.y, p1.z + x1.z, p1.w + x1.w};
        float s1 = 0.f, s2 = 0.f;
        #pragma unroll
        for (int u = 0; u < 8; ++u) { s1 += v[u]; s2 += v[u] * v[u]; }
        #pragma unroll
        for (int off = 1; off < 64; off <<= 1) { s1 += __shfl_xor(s1, off); s2 += __shfl_xor(s2, off); }
        float mean = s1 * (1.f / 512.f);
        float var  = s2 * (1.f / 512.f) - mean * mean;
        float rstd = rsqrtf(var + 1e-5f);
        int f0i = lane * 8;
        float4 g0 = *(const float4*)(gamma + f0i);
        float4 g1 = *(const float4*)(gamma + f0i + 4);
        float4 be0 = *(const float4*)(beta + f0i);
        float4 be1 = *(const float4*)(beta + f0i + 4);
        float* op = out + (((size_t)((b << 10) + ig)) << 9) + f0i;
        float4 o0, o1;
        o0.x = (v[0] - mean) * rstd * g0.x + be0.x;
        o0.y = (v[1] - mean) * rstd * g0.y + be0.y;
        o0.z = (v[2] - mean) * rstd * g0.z + be0.z;
        o0.w = (v[3] - mean) * rstd * g0.w + be0.w;
        o1.x = (v[4] - mean) * rstd * g1.x + be1.x;
        o1.y = (v[5] - mean) * rstd * g1.y + be1.y;
        o1.z = (v[6] - mean) * rstd * g1.z + be1.z;
        o1.w = (v[7] - mean) * rstd * g1.w + be1.w;
        *(float4*)op = o0;
        *(float4*)(op + 4) = o1;
    }
}

extern "C" void kernel_launch(void* const* d_in, const int* in_sizes, int n_in,
                              void* d_out, int out_size, void* d_ws, size_t ws_size,
                              hipStream_t stream) {
    const float* x     = (const float*)d_in[0];
    const int*   mask  = (const int*)d_in[1];
    const float* W     = (const float*)d_in[2];
    const float* a_src = (const float*)d_in[3];
    const float* a_dst = (const float*)d_in[4];
    const float* gamma = (const float*)d_in[5];
    const float* beta  = (const float*)d_in[6];
    float* out = (float*)d_out;

    ushort* hT = (ushort*)d_ws;                            // 8 MB
    ushort* Wc = hT + (size_t)8 * 512 * 1024;              // 0.5 MB
    float* ei = (float*)(Wc + (size_t)512 * 512);          // 128 KB
    float* ej = ei + 32768;                                // 128 KB

    conv_w<<<dim3(64), 256, 0, stream>>>(W, Wc);
    gemm_xw<<<dim3(512), 256, 0, stream>>>(x, Wc, a_src, a_dst, hT, ei, ej);
    attn_pv<<<dim3(256), 512, 0, stream>>>(hT, ei, ej, mask, x, gamma, beta, out);
}